// Round 9
// baseline (156.738 us; speedup 1.0000x reference)
//
#include <hip/hip_runtime.h>

// EncoderTreeRNN — R9: tree GEMMs on mfma_f32_32x32x16_f16, 2 row-groups x 4 col-groups.
// Each wave reads only its row-group's A rows -> 4x less LDS A-traffic than R8.
// Tree (word=0): z=sigm(hl Uzl+hr Uzr+bz), r=sigm(hl Url+hr Urr+br),
//                h~=tanh((r*hl)Uhl+(r*hr)Uhr+bh), out=z*(hl+hr)+(1-z)*h~
// K interleaved (k'=2j -> hl[j], 2j+1 -> hr[j]); U rows permuted to match.
// U frag layout (32x32): Uf[((cg*16+ks)*64+l)*8+j] = U'[ks*16+(l>>5)*8+j][cg*32+(l&31)].
// h1 vocab table (16x16 path, unchanged from R8): t1[v] = (1-z)*tanh(...), L1 gathers via tokens.

typedef _Float16 half_t;
typedef __attribute__((ext_vector_type(8))) _Float16 f16x8;
typedef __attribute__((ext_vector_type(4))) float f32x4;
typedef __attribute__((ext_vector_type(16))) float f32x16;

#define NTOK 262144
#define NB 4096
#define NV 100000

__device__ __forceinline__ float sigm(float x){
  float e = __expf(-x);
  return __builtin_amdgcn_rcpf(1.0f + e);
}
__device__ __forceinline__ float tanh_(float x){
  float xc = fminf(fmaxf(x,-15.f),15.f);
  float e = __expf(2.f*xc);
  return (e - 1.f) * __builtin_amdgcn_rcpf(e + 1.f);
}

// bc[0:128)=bWz+bUzl+bUzr, [128:256)=bWr+bUrl+bUrr, [256:384)=bWh+bUhl+bUhr
__global__ void bias_k(const float* bWz,const float* bUzl,const float* bUzr,
                       const float* bWr,const float* bUrl,const float* bUrr,
                       const float* bWh,const float* bUhl,const float* bUhr, float* bc){
  int j = threadIdx.x;
  if (j < 128)      bc[j] = bWz[j]+bUzl[j]+bUzr[j];
  else if (j < 256){ int i=j-128; bc[j] = bWr[i]+bUrl[i]+bUrr[i]; }
  else if (j < 384){ int i=j-256; bc[j] = bWh[i]+bUhl[i]+bUhr[i]; }
}

// W (16x16 frag, K=128, for h1tab): Wf[((w*4+ks)*64+l)*8+j] = W[ks*32+(l>>4)*8+j][w*16+(l&15)]
// U (32x32 frag, K=256 interleaved): see header comment.
__global__ __launch_bounds__(256) void wprep_k(
    const float* Wz, const float* Wh,
    const float* Uzl,const float* Uzr,const float* Url,const float* Urr,
    const float* Uhl,const float* Uhr, half_t* wb){
  int idx = blockIdx.x*256 + threadIdx.x;           // 131072 total
  if (idx < 32768){                                  // Wz_f, Wh_f (16x16 layout)
    const float* W = (idx < 16384) ? Wz : Wh;
    int t = idx & 16383;
    int w = t >> 11, ks = (t >> 9) & 3, l = (t >> 3) & 63, j = t & 7;
    int n = w*16 + (l & 15);
    int k = ks*32 + ((l >> 4) << 3) + j;
    wb[idx] = (half_t)W[k*128 + n];
  } else {                                           // Uz_f, Ur_f, Uh_f (32x32 layout)
    int t = idx - 32768;
    int mat = t >> 15;                               // 0=z,1=r,2=h
    t &= 32767;
    int cg = t >> 13, ks = (t >> 9) & 15, l = (t >> 3) & 63, j = t & 7;
    int n = cg*32 + (l & 31);
    int kp = ks*16 + ((l >> 5) << 3) + j;            // 0..255 interleaved
    int k = kp >> 1;
    const float* U;
    if (mat == 0) U = (kp & 1) ? Uzr : Uzl;
    else if (mat == 1) U = (kp & 1) ? Urr : Url;
    else U = (kp & 1) ? Uhr : Uhl;
    wb[idx] = (half_t)U[k*128 + n];
  }
}

// Vocab table (16x16 path): t1[v] = (1-z)*tanh(xWh+bh), z=sigm(xWz+bz). Sequential rows.
template<int MT>
__global__ __launch_bounds__(512, 4) void h1tab_k(
    const float* __restrict__ emb,
    const half_t* __restrict__ Wz_f, const half_t* __restrict__ Wh_f,
    const float* __restrict__ bc, half_t* __restrict__ t1)
{
  __shared__ __align__(16) _Float16 xs[MT*16][136];
  const int tid = threadIdx.x;
  const int m0  = blockIdx.x*(MT*16);
  #pragma unroll
  for (int it = 0; it < MT; it++){
    int idx = it*512 + tid;
    int m = idx >> 5, c = idx & 31;
    int row = m0 + m; if (row >= NV) row = 0;
    float4 v = ((const float4*)(emb + (size_t)row*128))[c];
    union { half_t h[4]; ushort4 u; } p;
    p.h[0]=(half_t)v.x; p.h[1]=(half_t)v.y; p.h[2]=(half_t)v.z; p.h[3]=(half_t)v.w;
    *(ushort4*)&xs[m][c*4] = p.u;
  }
  __syncthreads();
  const int w = tid>>6, l = tid&63;
  const int lr = l&15, lk = (l>>4)*8, lq = (l>>4)*4;
  const int col = w*16 + lr;

  f32x4 zacc[MT] = {}; f32x4 hacc[MT] = {};
  const half_t* wzp = Wz_f + ((w*4)*64 + l)*8;
  const half_t* whp = Wh_f + ((w*4)*64 + l)*8;
  f16x8 bz_n = *(const f16x8*)wzp;
  f16x8 bh_n = *(const f16x8*)whp;
  #pragma unroll
  for (int ks=0; ks<4; ks++){
    f16x8 bz = bz_n, bh = bh_n;
    if (ks < 3){
      bz_n = *(const f16x8*)(wzp + (ks+1)*512);
      bh_n = *(const f16x8*)(whp + (ks+1)*512);
    }
    #pragma unroll
    for (int mt=0; mt<MT; mt++){
      f16x8 a = *(const f16x8*)&xs[mt*16 + lr][ks*32 + lk];
      zacc[mt] = __builtin_amdgcn_mfma_f32_16x16x32_f16(a, bz, zacc[mt],0,0,0);
      hacc[mt] = __builtin_amdgcn_mfma_f32_16x16x32_f16(a, bh, hacc[mt],0,0,0);
    }
  }
  const float bzv = bc[col], bhv = bc[256+col];
  #pragma unroll
  for (int mt=0; mt<MT; mt++){
    #pragma unroll
    for (int q=0; q<4; q++){
      int row = m0 + mt*16 + lq + q;
      if (row < NV){
        float z  = sigm(zacc[mt][q] + bzv);
        float ht = tanh_(hacc[mt][q] + bhv);
        t1[(size_t)row*128 + col] = (half_t)((1.f-z)*ht);
      }
    }
  }
}

// Tree level, 32x32 MFMA. Waves: WR row-groups x 4 col-groups. ROWS = WR*MT*32 per block.
// C/D: col=lane&31, row=(reg&3)+8*(reg>>2)+4*(lane>>5). A/B frag: row/col=l&31, k=(l>>5)*8+j.
template<int MT, int WR, int GATHER>
__global__ __launch_bounds__(WR*256, 4) void tree_k(
    const half_t* __restrict__ hin, const int* __restrict__ tokens,
    half_t* __restrict__ hout, float* __restrict__ outf,
    const half_t* __restrict__ Uz_f, const half_t* __restrict__ Ur_f, const half_t* __restrict__ Uh_f,
    const float* __restrict__ bc, int last)
{
  constexpr int ROWS = WR*MT*32;
  constexpr int THREADS = WR*256;
  __shared__ __align__(16) _Float16 xs[ROWS][264];   // 528B stride === 4 dw mod 32
  const int tid = threadIdx.x;
  const int m0  = blockIdx.x*ROWS;
  // stage interleaved: xs[m][2j]=hl[m][j], xs[m][2j+1]=hr[m][j]
  #pragma unroll
  for (int it = 0; it < MT*4; it++){
    int idx = it*THREADS + tid;                 // ROWS x 32 chunks
    int m = idx >> 5, c = idx & 31;
    const half_t *pl, *pr;
    if (GATHER){
      int tl = tokens[2*(m0+m)], tr = tokens[2*(m0+m)+1];
      pl = hin + (size_t)tl*128 + c*4;
      pr = hin + (size_t)tr*128 + c*4;
    } else {
      size_t base = (size_t)(2*(m0+m))*128 + c*4;
      pl = hin + base;
      pr = hin + base + 128;
    }
    uint2 A  = *(const uint2*)pl;
    uint2 Bv = *(const uint2*)pr;
    uint4 o;
    o.x = (A.x & 0xFFFFu) | (Bv.x << 16);
    o.y = (A.x >> 16)     | (Bv.x & 0xFFFF0000u);
    o.z = (A.y & 0xFFFFu) | (Bv.y << 16);
    o.w = (A.y >> 16)     | (Bv.y & 0xFFFF0000u);
    *(uint4*)&xs[m][c*8] = o;
  }
  __syncthreads();
  const int w = tid>>6, l = tid&63;
  const int cg = w & 3, rg = w >> 2;
  const int lc = l & 31, hi = l >> 5;
  const int lk8 = hi*8;
  const int col = cg*32 + lc;
  const int rowbase = rg*(MT*32);

  // --- z & r GEMMs ---
  f32x16 zacc[MT] = {}; f32x16 racc[MT] = {};
  const half_t* uzp = Uz_f + ((cg*16)*64 + l)*8;
  const half_t* urp = Ur_f + ((cg*16)*64 + l)*8;
  f16x8 bz_n = *(const f16x8*)uzp;
  f16x8 br_n = *(const f16x8*)urp;
  #pragma unroll
  for (int ks=0; ks<16; ks++){
    f16x8 bz = bz_n, br = br_n;
    if (ks < 15){
      bz_n = *(const f16x8*)(uzp + (ks+1)*512);
      br_n = *(const f16x8*)(urp + (ks+1)*512);
    }
    #pragma unroll
    for (int mt=0; mt<MT; mt++){
      f16x8 a = *(const f16x8*)&xs[rowbase + mt*32 + lc][ks*16 + lk8];
      zacc[mt] = __builtin_amdgcn_mfma_f32_32x32x16_f16(a, bz, zacc[mt],0,0,0);
      racc[mt] = __builtin_amdgcn_mfma_f32_32x32x16_f16(a, br, racc[mt],0,0,0);
    }
  }
  __syncthreads();   // all reads of raw h done

  // --- elementwise: b32 read -> {hl,hr}; write back {r*hl,r*hr}; carry z,s packed f16 ---
  uint zp[MT][8], sp[MT][8];
  const float bzv = bc[col], brv = bc[128+col];
  #pragma unroll
  for (int mt=0; mt<MT; mt++){
    union { half_t h[16]; uint u[8]; } pz, ps;
    #pragma unroll
    for (int r=0; r<16; r++){
      int row = rowbase + mt*32 + (r&3) + 8*(r>>2) + 4*hi;
      union { uint u; half_t h[2]; } io;
      io.u = *(uint*)&xs[row][2*col];
      float hl = (float)io.h[0];
      float hr = (float)io.h[1];
      float z  = sigm(zacc[mt][r] + bzv);
      float rv = sigm(racc[mt][r] + brv);
      pz.h[r] = (half_t)z;
      ps.h[r] = (half_t)(hl + hr);
      io.h[0] = (half_t)(rv*hl);
      io.h[1] = (half_t)(rv*hr);
      *(uint*)&xs[row][2*col] = io.u;
    }
    #pragma unroll
    for (int u8=0; u8<8; u8++){ zp[mt][u8]=pz.u[u8]; sp[mt][u8]=ps.u[u8]; }
  }
  __syncthreads();

  // --- h~ GEMM over interleaved (r*hl,r*hr) ---
  f32x16 ha[MT] = {};
  const half_t* uhp = Uh_f + ((cg*16)*64 + l)*8;
  f16x8 bh_n = *(const f16x8*)uhp;
  #pragma unroll
  for (int ks=0; ks<16; ks++){
    f16x8 bh = bh_n;
    if (ks < 15) bh_n = *(const f16x8*)(uhp + (ks+1)*512);
    #pragma unroll
    for (int mt=0; mt<MT; mt++){
      f16x8 a = *(const f16x8*)&xs[rowbase + mt*32 + lc][ks*16 + lk8];
      ha[mt] = __builtin_amdgcn_mfma_f32_32x32x16_f16(a, bh, ha[mt],0,0,0);
    }
  }
  // --- combine + store ---
  const float bhv = bc[256+col];
  #pragma unroll
  for (int mt=0; mt<MT; mt++){
    union { half_t h[16]; uint u[8]; } pz, ps;
    #pragma unroll
    for (int u8=0; u8<8; u8++){ pz.u[u8]=zp[mt][u8]; ps.u[u8]=sp[mt][u8]; }
    #pragma unroll
    for (int r=0; r<16; r++){
      int row = rowbase + mt*32 + (r&3) + 8*(r>>2) + 4*hi;
      float ht = tanh_(ha[mt][r] + bhv);
      float z  = (float)pz.h[r];
      float o  = z*(float)ps.h[r] + (1.f-z)*ht;
      size_t off = (size_t)(m0+row)*128 + col;
      if (last) outf[off] = o;
      else      hout[off] = (half_t)o;
    }
  }
}

extern "C" void kernel_launch(void* const* d_in, const int* in_sizes, int n_in,
                              void* d_out, int out_size, void* d_ws, size_t ws_size,
                              hipStream_t stream) {
  const int*   tokens = (const int*)  d_in[0];
  const float* emb    = (const float*)d_in[1];
  const float* Wz  = (const float*)d_in[2];  const float* bWz  = (const float*)d_in[3];
  const float* Uzl = (const float*)d_in[4];  const float* bUzl = (const float*)d_in[5];
  const float* Uzr = (const float*)d_in[6];  const float* bUzr = (const float*)d_in[7];
  const float* Wr  = (const float*)d_in[8];  const float* bWr  = (const float*)d_in[9];
  const float* Url = (const float*)d_in[10]; const float* bUrl = (const float*)d_in[11];
  const float* Urr = (const float*)d_in[12]; const float* bUrr = (const float*)d_in[13];
  const float* Wh  = (const float*)d_in[14]; const float* bWh  = (const float*)d_in[15];
  const float* Uhl = (const float*)d_in[16]; const float* bUhl = (const float*)d_in[17];
  const float* Uhr = (const float*)d_in[18]; const float* bUhr = (const float*)d_in[19];

  float*  bc = (float*)d_ws;
  half_t* wb = (half_t*)((char*)d_ws + 4096);
  half_t* Wz_f = wb;
  half_t* Wh_f = wb + 16384;
  half_t* Uz_f = wb + 32768;
  half_t* Ur_f = wb + 65536;
  half_t* Uh_f = wb + 98304;
  half_t* t1 = (half_t*)((char*)d_ws + (1<<20));     // 100000*128 f16 = 25.6 MB
  half_t* hA = t1 + (size_t)NV*128;                  // 131072*128 f16 = 33.5 MB
  half_t* hB = hA + (size_t)(NTOK/2)*128;            // 65536*128 f16 = 16.8 MB

  bias_k<<<1, 384, 0, stream>>>(bWz,bUzl,bUzr,bWr,bUrl,bUrr,bWh,bUhl,bUhr, bc);
  wprep_k<<<512, 256, 0, stream>>>(Wz,Wh,Uzl,Uzr,Url,Urr,Uhl,Uhr, wb);

  h1tab_k<8><<<(NV + 127)/128, 512, 0, stream>>>(emb, Wz_f, Wh_f, bc, t1);

  float* outf = (float*)d_out;
  // L1: gather from t1, M=131072
  tree_k<2,2,1><<<1024, 512, 0, stream>>>(t1, tokens, hA, outf, Uz_f, Ur_f, Uh_f, bc, 0);
  // L2: 65536
  tree_k<2,2,0><<<512, 512, 0, stream>>>(hA, tokens, hB, outf, Uz_f, Ur_f, Uh_f, bc, 0);
  // L3: 32768
  tree_k<2,2,0><<<256, 512, 0, stream>>>(hB, tokens, hA, outf, Uz_f, Ur_f, Uh_f, bc, 0);
  // L4: 16384
  tree_k<2,2,0><<<128, 512, 0, stream>>>(hA, tokens, hB, outf, Uz_f, Ur_f, Uh_f, bc, 0);
  // L5: 8192
  tree_k<1,2,0><<<128, 512, 0, stream>>>(hB, tokens, hA, outf, Uz_f, Ur_f, Uh_f, bc, 0);
  // L6: 4096 -> d_out (f32)
  tree_k<1,1,0><<<128, 256, 0, stream>>>(hA, tokens, hB, outf, Uz_f, Ur_f, Uh_f, bc, 1);
}

// Round 10
// 155.153 us; speedup vs baseline: 1.0102x; 1.0102x over previous
//
#include <hip/hip_runtime.h>

// EncoderTreeRNN — R10: occupancy push. ROWS=64 tree blocks (LDS 33.8KB -> 3-4 blocks/CU),
// __launch_bounds__(512,6). Same 32x32-MFMA math as R9 (verified absmax 0.0039).
// Tree (word=0): z=sigm(hl Uzl+hr Uzr+bz), r=sigm(hl Url+hr Urr+br),
//                h~=tanh((r*hl)Uhl+(r*hr)Uhr+bh), out=z*(hl+hr)+(1-z)*h~
// K interleaved (k'=2j -> hl[j], 2j+1 -> hr[j]); U rows permuted to match.
// U frag layout (32x32): Uf[((cg*16+ks)*64+l)*8+j] = U'[ks*16+(l>>5)*8+j][cg*32+(l&31)].
// h1 vocab table (16x16 path): t1[v] = (1-z)*tanh(...), tree L1 gathers via tokens.

typedef _Float16 half_t;
typedef __attribute__((ext_vector_type(8))) _Float16 f16x8;
typedef __attribute__((ext_vector_type(4))) float f32x4;
typedef __attribute__((ext_vector_type(16))) float f32x16;

#define NTOK 262144
#define NB 4096
#define NV 100000

__device__ __forceinline__ float sigm(float x){
  float e = __expf(-x);
  return __builtin_amdgcn_rcpf(1.0f + e);
}
__device__ __forceinline__ float tanh_(float x){
  float xc = fminf(fmaxf(x,-15.f),15.f);
  float e = __expf(2.f*xc);
  return (e - 1.f) * __builtin_amdgcn_rcpf(e + 1.f);
}

// bc[0:128)=bWz+bUzl+bUzr, [128:256)=bWr+bUrl+bUrr, [256:384)=bWh+bUhl+bUhr
__global__ void bias_k(const float* bWz,const float* bUzl,const float* bUzr,
                       const float* bWr,const float* bUrl,const float* bUrr,
                       const float* bWh,const float* bUhl,const float* bUhr, float* bc){
  int j = threadIdx.x;
  if (j < 128)      bc[j] = bWz[j]+bUzl[j]+bUzr[j];
  else if (j < 256){ int i=j-128; bc[j] = bWr[i]+bUrl[i]+bUrr[i]; }
  else if (j < 384){ int i=j-256; bc[j] = bWh[i]+bUhl[i]+bUhr[i]; }
}

// W (16x16 frag, K=128): Wf[((w*4+ks)*64+l)*8+j] = W[ks*32+(l>>4)*8+j][w*16+(l&15)]
// U (32x32 frag, K=256 interleaved): see header.
__global__ __launch_bounds__(256) void wprep_k(
    const float* Wz, const float* Wh,
    const float* Uzl,const float* Uzr,const float* Url,const float* Urr,
    const float* Uhl,const float* Uhr, half_t* wb){
  int idx = blockIdx.x*256 + threadIdx.x;           // 131072 total
  if (idx < 32768){                                  // Wz_f, Wh_f (16x16 layout)
    const float* W = (idx < 16384) ? Wz : Wh;
    int t = idx & 16383;
    int w = t >> 11, ks = (t >> 9) & 3, l = (t >> 3) & 63, j = t & 7;
    int n = w*16 + (l & 15);
    int k = ks*32 + ((l >> 4) << 3) + j;
    wb[idx] = (half_t)W[k*128 + n];
  } else {                                           // Uz_f, Ur_f, Uh_f (32x32 layout)
    int t = idx - 32768;
    int mat = t >> 15;                               // 0=z,1=r,2=h
    t &= 32767;
    int cg = t >> 13, ks = (t >> 9) & 15, l = (t >> 3) & 63, j = t & 7;
    int n = cg*32 + (l & 31);
    int kp = ks*16 + ((l >> 5) << 3) + j;            // 0..255 interleaved
    int k = kp >> 1;
    const float* U;
    if (mat == 0) U = (kp & 1) ? Uzr : Uzl;
    else if (mat == 1) U = (kp & 1) ? Urr : Url;
    else U = (kp & 1) ? Uhr : Uhl;
    wb[idx] = (half_t)U[k*128 + n];
  }
}

// Vocab table (16x16 path): t1[v] = (1-z)*tanh(xWh+bh), z=sigm(xWz+bz). Sequential rows.
template<int MT>
__global__ __launch_bounds__(512, 6) void h1tab_k(
    const float* __restrict__ emb,
    const half_t* __restrict__ Wz_f, const half_t* __restrict__ Wh_f,
    const float* __restrict__ bc, half_t* __restrict__ t1)
{
  __shared__ __align__(16) _Float16 xs[MT*16][136];
  const int tid = threadIdx.x;
  const int m0  = blockIdx.x*(MT*16);
  #pragma unroll
  for (int it = 0; it < MT; it++){
    int idx = it*512 + tid;
    int m = idx >> 5, c = idx & 31;
    int row = m0 + m; if (row >= NV) row = 0;
    float4 v = ((const float4*)(emb + (size_t)row*128))[c];
    union { half_t h[4]; ushort4 u; } p;
    p.h[0]=(half_t)v.x; p.h[1]=(half_t)v.y; p.h[2]=(half_t)v.z; p.h[3]=(half_t)v.w;
    *(ushort4*)&xs[m][c*4] = p.u;
  }
  __syncthreads();
  const int w = tid>>6, l = tid&63;
  const int lr = l&15, lk = (l>>4)*8, lq = (l>>4)*4;
  const int col = w*16 + lr;

  f32x4 zacc[MT] = {}; f32x4 hacc[MT] = {};
  const half_t* wzp = Wz_f + ((w*4)*64 + l)*8;
  const half_t* whp = Wh_f + ((w*4)*64 + l)*8;
  f16x8 bz_n = *(const f16x8*)wzp;
  f16x8 bh_n = *(const f16x8*)whp;
  #pragma unroll
  for (int ks=0; ks<4; ks++){
    f16x8 bz = bz_n, bh = bh_n;
    if (ks < 3){
      bz_n = *(const f16x8*)(wzp + (ks+1)*512);
      bh_n = *(const f16x8*)(whp + (ks+1)*512);
    }
    #pragma unroll
    for (int mt=0; mt<MT; mt++){
      f16x8 a = *(const f16x8*)&xs[mt*16 + lr][ks*32 + lk];
      zacc[mt] = __builtin_amdgcn_mfma_f32_16x16x32_f16(a, bz, zacc[mt],0,0,0);
      hacc[mt] = __builtin_amdgcn_mfma_f32_16x16x32_f16(a, bh, hacc[mt],0,0,0);
    }
  }
  const float bzv = bc[col], bhv = bc[256+col];
  #pragma unroll
  for (int mt=0; mt<MT; mt++){
    #pragma unroll
    for (int q=0; q<4; q++){
      int row = m0 + mt*16 + lq + q;
      if (row < NV){
        float z  = sigm(zacc[mt][q] + bzv);
        float ht = tanh_(hacc[mt][q] + bhv);
        t1[(size_t)row*128 + col] = (half_t)((1.f-z)*ht);
      }
    }
  }
}

// Tree level, 32x32 MFMA. WR row-groups x 4 col-groups of waves. ROWS = WR*MT*32.
// C/D: col=lane&31, row=(reg&3)+8*(reg>>2)+4*(lane>>5). A/B frag: row/col=l&31, k=(l>>5)*8+j.
template<int MT, int WR, int GATHER>
__global__ __launch_bounds__(WR*256, 6) void tree_k(
    const half_t* __restrict__ hin, const int* __restrict__ tokens,
    half_t* __restrict__ hout, float* __restrict__ outf,
    const half_t* __restrict__ Uz_f, const half_t* __restrict__ Ur_f, const half_t* __restrict__ Uh_f,
    const float* __restrict__ bc, int last)
{
  constexpr int ROWS = WR*MT*32;
  constexpr int THREADS = WR*256;
  __shared__ __align__(16) _Float16 xs[ROWS][264];   // 528B stride === 4 dw mod 32
  const int tid = threadIdx.x;
  const int m0  = blockIdx.x*ROWS;
  // stage interleaved: xs[m][2j]=hl[m][j], xs[m][2j+1]=hr[m][j]
  #pragma unroll
  for (int it = 0; it < MT*4; it++){
    int idx = it*THREADS + tid;                 // ROWS x 32 chunks
    int m = idx >> 5, c = idx & 31;
    const half_t *pl, *pr;
    if (GATHER){
      int tl = tokens[2*(m0+m)], tr = tokens[2*(m0+m)+1];
      pl = hin + (size_t)tl*128 + c*4;
      pr = hin + (size_t)tr*128 + c*4;
    } else {
      size_t base = (size_t)(2*(m0+m))*128 + c*4;
      pl = hin + base;
      pr = hin + base + 128;
    }
    uint2 A  = *(const uint2*)pl;
    uint2 Bv = *(const uint2*)pr;
    uint4 o;
    o.x = (A.x & 0xFFFFu) | (Bv.x << 16);
    o.y = (A.x >> 16)     | (Bv.x & 0xFFFF0000u);
    o.z = (A.y & 0xFFFFu) | (Bv.y << 16);
    o.w = (A.y >> 16)     | (Bv.y & 0xFFFF0000u);
    *(uint4*)&xs[m][c*8] = o;
  }
  __syncthreads();
  const int w = tid>>6, l = tid&63;
  const int cg = w & 3, rg = w >> 2;
  const int lc = l & 31, hi = l >> 5;
  const int lk8 = hi*8;
  const int col = cg*32 + lc;
  const int rowbase = rg*(MT*32);

  // --- z & r GEMMs ---
  f32x16 zacc[MT] = {}; f32x16 racc[MT] = {};
  const half_t* uzp = Uz_f + ((cg*16)*64 + l)*8;
  const half_t* urp = Ur_f + ((cg*16)*64 + l)*8;
  f16x8 bz_n = *(const f16x8*)uzp;
  f16x8 br_n = *(const f16x8*)urp;
  #pragma unroll
  for (int ks=0; ks<16; ks++){
    f16x8 bz = bz_n, br = br_n;
    if (ks < 15){
      bz_n = *(const f16x8*)(uzp + (ks+1)*512);
      br_n = *(const f16x8*)(urp + (ks+1)*512);
    }
    #pragma unroll
    for (int mt=0; mt<MT; mt++){
      f16x8 a = *(const f16x8*)&xs[rowbase + mt*32 + lc][ks*16 + lk8];
      zacc[mt] = __builtin_amdgcn_mfma_f32_32x32x16_f16(a, bz, zacc[mt],0,0,0);
      racc[mt] = __builtin_amdgcn_mfma_f32_32x32x16_f16(a, br, racc[mt],0,0,0);
    }
  }
  __syncthreads();   // all reads of raw h done

  // --- elementwise: b32 read -> {hl,hr}; write back {r*hl,r*hr}; carry z,s packed f16 ---
  uint zp[MT][8], sp[MT][8];
  const float bzv = bc[col], brv = bc[128+col];
  #pragma unroll
  for (int mt=0; mt<MT; mt++){
    union { half_t h[16]; uint u[8]; } pz, ps;
    #pragma unroll
    for (int r=0; r<16; r++){
      int row = rowbase + mt*32 + (r&3) + 8*(r>>2) + 4*hi;
      union { uint u; half_t h[2]; } io;
      io.u = *(uint*)&xs[row][2*col];
      float hl = (float)io.h[0];
      float hr = (float)io.h[1];
      float z  = sigm(zacc[mt][r] + bzv);
      float rv = sigm(racc[mt][r] + brv);
      pz.h[r] = (half_t)z;
      ps.h[r] = (half_t)(hl + hr);
      io.h[0] = (half_t)(rv*hl);
      io.h[1] = (half_t)(rv*hr);
      *(uint*)&xs[row][2*col] = io.u;
    }
    #pragma unroll
    for (int u8=0; u8<8; u8++){ zp[mt][u8]=pz.u[u8]; sp[mt][u8]=ps.u[u8]; }
  }
  __syncthreads();

  // --- h~ GEMM over interleaved (r*hl,r*hr) ---
  f32x16 ha[MT] = {};
  const half_t* uhp = Uh_f + ((cg*16)*64 + l)*8;
  f16x8 bh_n = *(const f16x8*)uhp;
  #pragma unroll
  for (int ks=0; ks<16; ks++){
    f16x8 bh = bh_n;
    if (ks < 15) bh_n = *(const f16x8*)(uhp + (ks+1)*512);
    #pragma unroll
    for (int mt=0; mt<MT; mt++){
      f16x8 a = *(const f16x8*)&xs[rowbase + mt*32 + lc][ks*16 + lk8];
      ha[mt] = __builtin_amdgcn_mfma_f32_32x32x16_f16(a, bh, ha[mt],0,0,0);
    }
  }
  // --- combine + store ---
  const float bhv = bc[256+col];
  #pragma unroll
  for (int mt=0; mt<MT; mt++){
    union { half_t h[16]; uint u[8]; } pz, ps;
    #pragma unroll
    for (int u8=0; u8<8; u8++){ pz.u[u8]=zp[mt][u8]; ps.u[u8]=sp[mt][u8]; }
    #pragma unroll
    for (int r=0; r<16; r++){
      int row = rowbase + mt*32 + (r&3) + 8*(r>>2) + 4*hi;
      float ht = tanh_(ha[mt][r] + bhv);
      float z  = (float)pz.h[r];
      float o  = z*(float)ps.h[r] + (1.f-z)*ht;
      size_t off = (size_t)(m0+row)*128 + col;
      if (last) outf[off] = o;
      else      hout[off] = (half_t)o;
    }
  }
}

extern "C" void kernel_launch(void* const* d_in, const int* in_sizes, int n_in,
                              void* d_out, int out_size, void* d_ws, size_t ws_size,
                              hipStream_t stream) {
  const int*   tokens = (const int*)  d_in[0];
  const float* emb    = (const float*)d_in[1];
  const float* Wz  = (const float*)d_in[2];  const float* bWz  = (const float*)d_in[3];
  const float* Uzl = (const float*)d_in[4];  const float* bUzl = (const float*)d_in[5];
  const float* Uzr = (const float*)d_in[6];  const float* bUzr = (const float*)d_in[7];
  const float* Wr  = (const float*)d_in[8];  const float* bWr  = (const float*)d_in[9];
  const float* Url = (const float*)d_in[10]; const float* bUrl = (const float*)d_in[11];
  const float* Urr = (const float*)d_in[12]; const float* bUrr = (const float*)d_in[13];
  const float* Wh  = (const float*)d_in[14]; const float* bWh  = (const float*)d_in[15];
  const float* Uhl = (const float*)d_in[16]; const float* bUhl = (const float*)d_in[17];
  const float* Uhr = (const float*)d_in[18]; const float* bUhr = (const float*)d_in[19];

  float*  bc = (float*)d_ws;
  half_t* wb = (half_t*)((char*)d_ws + 4096);
  half_t* Wz_f = wb;
  half_t* Wh_f = wb + 16384;
  half_t* Uz_f = wb + 32768;
  half_t* Ur_f = wb + 65536;
  half_t* Uh_f = wb + 98304;
  half_t* t1 = (half_t*)((char*)d_ws + (1<<20));     // 100000*128 f16 = 25.6 MB
  half_t* hA = t1 + (size_t)NV*128;                  // 131072*128 f16 = 33.5 MB
  half_t* hB = hA + (size_t)(NTOK/2)*128;            // 65536*128 f16 = 16.8 MB

  bias_k<<<1, 384, 0, stream>>>(bWz,bUzl,bUzr,bWr,bUrl,bUrr,bWh,bUhl,bUhr, bc);
  wprep_k<<<512, 256, 0, stream>>>(Wz,Wh,Uzl,Uzr,Url,Urr,Uhl,Uhr, wb);

  h1tab_k<4><<<(NV + 63)/64, 512, 0, stream>>>(emb, Wz_f, Wh_f, bc, t1);

  float* outf = (float*)d_out;
  // ROWS=64 blocks everywhere (LDS 33.8KB -> 3-4 blocks/CU)
  tree_k<1,2,1><<<2048, 512, 0, stream>>>(t1, tokens, hA, outf, Uz_f, Ur_f, Uh_f, bc, 0); // L1 131072
  tree_k<1,2,0><<<1024, 512, 0, stream>>>(hA, tokens, hB, outf, Uz_f, Ur_f, Uh_f, bc, 0); // L2 65536
  tree_k<1,2,0><<<512,  512, 0, stream>>>(hB, tokens, hA, outf, Uz_f, Ur_f, Uh_f, bc, 0); // L3 32768
  tree_k<1,2,0><<<256,  512, 0, stream>>>(hA, tokens, hB, outf, Uz_f, Ur_f, Uh_f, bc, 0); // L4 16384
  tree_k<1,2,0><<<128,  512, 0, stream>>>(hB, tokens, hA, outf, Uz_f, Ur_f, Uh_f, bc, 0); // L5 8192
  tree_k<1,2,0><<<64,   512, 0, stream>>>(hA, tokens, hB, outf, Uz_f, Ur_f, Uh_f, bc, 1); // L6 4096 -> f32 out
}